// Round 6
// baseline (154.170 us; speedup 1.0000x reference)
//
#include <hip/hip_runtime.h>

#define B_ 4
#define L_ 4096
#define D_ 64
#define N_ 16
#define CHUNK 16
#define NCHUNK (L_ / CHUNK)        // 256
#define TOTCHUNK (B_ * NCHUNK)     // 1024

constexpr float DT_  = 0.1f;
constexpr float EPS_ = 1e-6f;

// ---------------------------------------------------------------------------
// K1: fused projection + local chunk scan + (for the last 16 blocks of each
// batch) the cross-chunk combine. 1024 blocks x 64 threads (1 wave).
//
// Per block (= one 16-step chunk): stage x->LDS; 16 interleaved delta
// butterflies; Bm/Cm dots (W rows in registers, K split across lane halves)
// -> a/g/cm in LDS; coalesced float4 copy of ag/cm to global P/Cm; local scan
// (zero init) -> S (chunk-final state) + Cdec (chunk decay).
//
// Then: __threadfence (release) + atomicAdd on ctr[batch]. Blocks that get
// old in [NCHUNK-16, NCHUNK) take combine role n = old-(NCHUNK-16): spin with
// agent-scope acquire until ctr[batch]==NCHUNK (all chunk states published),
// then run the 256-chunk exclusive scan for (batch, n) with distance-8
// software prefetch, converting S into chunk-initial states in place.
// Deadlock-free: role blocks have already incremented before spinning, and
// only 64 of 1024 resident block slots ever spin.
// ---------------------------------------------------------------------------
__global__ __launch_bounds__(64) void proj_scan_combine_kernel(
    const float* __restrict__ x,  const float* __restrict__ A,
    const float* __restrict__ Wb, const float* __restrict__ bb,
    const float* __restrict__ Wc, const float* __restrict__ bc,
    const float* __restrict__ Wd, const float* __restrict__ bd,
    float* __restrict__ P, float* __restrict__ Cm,
    float* __restrict__ S, float* __restrict__ Cdec,
    int* __restrict__ ctr)
{
    const int gc    = blockIdx.x;              // global chunk 0..1023
    const int batch = gc >> 8;                 // gc / NCHUNK
    const int c     = gc & (NCHUNK - 1);
    const int lane  = threadIdx.x;
    const int base0 = batch * L_ + c * CHUNK;

    __shared__ float xs[CHUNK * D_];           // 4 KB
    __shared__ float ag[CHUNK * 32];           // 2 KB
    __shared__ float cm[CHUNK * N_];           // 1 KB

    // ---- stage chunk's x ----
    const float4* xg  = (const float4*)(x + (size_t)base0 * D_);
    float4*       xsv = (float4*)xs;
    #pragma unroll
    for (int i = 0; i < 4; i++) xsv[i * 64 + lane] = xg[i * 64 + lane];

    // ---- W rows in registers (overlaps x staging latency) ----
    const int o  = lane & 31;                  // 0-15 -> Bm row, 16-31 -> Cm row
    const int h2 = lane >> 5;                  // K-half
    float wreg[32];
    const float* Wrow = (o < 16) ? (Wb + o * D_) : (Wc + (o - 16) * D_);
    const float4* w4p = (const float4*)(Wrow + h2 * 32);
    #pragma unroll
    for (int j = 0; j < 8; j++) {
        float4 w4 = w4p[j];
        wreg[4*j+0] = w4.x; wreg[4*j+1] = w4.y;
        wreg[4*j+2] = w4.z; wreg[4*j+3] = w4.w;
    }
    const float wd   = Wd[lane];
    const float bd0  = bd[0];
    const float An   = A[lane & 15];           // row 0 of (D,N); rows identical
    const float bias = (o < 16) ? bb[o] : bc[o - 16];

    __syncthreads();

    // ---- deltas: 16 butterflies, interleaved so shfl chains pipeline ----
    float r[CHUNK];
    #pragma unroll
    for (int p = 0; p < CHUNK; p++) r[p] = xs[p * D_ + lane] * wd;
    #pragma unroll
    for (int m = 32; m >= 1; m >>= 1) {
        #pragma unroll
        for (int p = 0; p < CHUNK; p++) r[p] += __shfl_xor(r[p], m, 64);
    }
    float delta[CHUNK];
    #pragma unroll
    for (int p = 0; p < CHUNK; p++) {
        float z = r[p] + bd0;
        delta[p] = fmaxf(z, 0.0f) + log1pf(expf(-fabsf(z))) + DT_;
    }

    // ---- Bm/Cm dots -> LDS ----
    #pragma unroll
    for (int p = 0; p < CHUNK; p++) {
        float acc = 0.0f;
        const float4* xs4 = (const float4*)(xs + p * D_ + h2 * 32);
        #pragma unroll
        for (int j = 0; j < 8; j++) {
            float4 v = xs4[j];                 // broadcast LDS reads
            acc += v.x * wreg[4*j+0] + v.y * wreg[4*j+1]
                 + v.z * wreg[4*j+2] + v.w * wreg[4*j+3];
        }
        acc += __shfl_xor(acc, 32, 64);        // lanes 0-31 hold full dots
        if (lane < 16) {
            float Bm  = acc + bias;
            float tmp = An * delta[p];
            float a   = expf(tmp);
            float g   = (a - 1.0f) * delta[p] * Bm / (tmp + EPS_);
            ag[p * 32 + lane]      = a;
            ag[p * 32 + 16 + lane] = g;
        } else if (lane < 32) {
            cm[p * 16 + (lane - 16)] = acc + bias;
        }
    }
    __syncthreads();

    // ---- coalesced float4 copy of ag/cm to global (for the replay kernel) --
    {
        float4*       Pg   = (float4*)(P + (size_t)base0 * 32);   // 128 float4
        const float4* agv4 = (const float4*)ag;
        Pg[lane]      = agv4[lane];
        Pg[64 + lane] = agv4[64 + lane];
        float4*       Cg   = (float4*)(Cm + (size_t)base0 * 16);  // 64 float4
        const float4* cmv4 = (const float4*)cm;
        Cg[lane] = cmv4[lane];
    }

    // ---- local scan (zero init), LDS-only inner loop ----
    float h[N_], cum[N_];
    #pragma unroll
    for (int n = 0; n < N_; n++) { h[n] = 0.0f; cum[n] = 1.0f; }
    for (int s = 0; s < CHUNK; s++) {
        float xd = xs[s * D_ + lane];
        const float4* row = (const float4*)(ag + s * 32);
        #pragma unroll
        for (int q = 0; q < 4; q++) {
            float4 a4 = row[q];
            float4 g4 = row[4 + q];
            h[4*q+0] = a4.x * h[4*q+0] + g4.x * xd;  cum[4*q+0] *= a4.x;
            h[4*q+1] = a4.y * h[4*q+1] + g4.y * xd;  cum[4*q+1] *= a4.y;
            h[4*q+2] = a4.z * h[4*q+2] + g4.z * xd;  cum[4*q+2] *= a4.z;
            h[4*q+3] = a4.w * h[4*q+3] + g4.w * xd;  cum[4*q+3] *= a4.w;
        }
    }
    #pragma unroll
    for (int n = 0; n < N_; n++)
        S[(size_t)(gc * N_ + n) * D_ + lane] = h[n];
    if (lane == 0) {
        #pragma unroll
        for (int n = 0; n < N_; n++) Cdec[gc * N_ + n] = cum[n];
    }

    // ---- publish + maybe take combine role ----
    __threadfence();                           // device-scope release of S/Cdec
    int old = 0;
    if (lane == 0) old = atomicAdd(&ctr[batch], 1);
    old = __shfl(old, 0, 64);

    if (old >= NCHUNK - 16) {
        const int nrole = old - (NCHUNK - 16); // unique n in [0,16) per batch
        // spin until this batch's 256 chunk states are all published
        while (__hip_atomic_load(&ctr[batch], __ATOMIC_ACQUIRE,
                                 __HIP_MEMORY_SCOPE_AGENT) < NCHUNK) {}
        __threadfence();                       // acquire for all lanes

        float*       baseS = S    + (size_t)(batch * NCHUNK * N_ + nrole) * D_ + lane;
        const float* baseA = Cdec + batch * NCHUNK * N_ + nrole;

        float run = 0.0f;
        float sbuf[8], abuf[8];
        #pragma unroll
        for (int j = 0; j < 8; j++) {
            sbuf[j] = baseS[(size_t)j * (N_ * D_)];
            abuf[j] = baseA[j * N_];
        }
        for (int cc = 0; cc < NCHUNK; cc += 8) {
            const int cn = (cc + 8 < NCHUNK) ? (cc + 8) : cc;  // last: dummy reload
            float t[8], u[8];
            #pragma unroll
            for (int j = 0; j < 8; j++) {
                t[j] = baseS[(size_t)(cn + j) * (N_ * D_)];
                u[j] = baseA[(cn + j) * N_];
            }
            #pragma unroll
            for (int j = 0; j < 8; j++) {
                baseS[(size_t)(cc + j) * (N_ * D_)] = run;     // exclusive prefix
                run = abuf[j] * run + sbuf[j];
            }
            #pragma unroll
            for (int j = 0; j < 8; j++) { sbuf[j] = t[j]; abuf[j] = u[j]; }
        }
    }
}

// ---------------------------------------------------------------------------
// K2: replay with true init; produce output. 1024 blocks x 64 threads.
// ---------------------------------------------------------------------------
__global__ __launch_bounds__(64) void scan_out(
    const float* __restrict__ x, const float* __restrict__ P,
    const float* __restrict__ Cmat, const float* __restrict__ S,
    float* __restrict__ out)
{
    const int gc    = blockIdx.x;
    const int batch = gc >> 8;
    const int c     = gc & (NCHUNK - 1);
    const int lane  = threadIdx.x;
    const int base0 = batch * L_ + c * CHUNK;

    __shared__ float xs[CHUNK * D_];         // 4 KB
    __shared__ float ag[CHUNK * 32];         // 2 KB
    __shared__ float cm[CHUNK * N_];         // 1 KB

    const float4* xg  = (const float4*)(x + (size_t)base0 * D_);
    float4*       xsv = (float4*)xs;
    #pragma unroll
    for (int i = 0; i < 4; i++) xsv[i * 64 + lane] = xg[i * 64 + lane];
    const float4* pg  = (const float4*)(P + (size_t)base0 * 32);
    float4*       agv = (float4*)ag;
    #pragma unroll
    for (int i = 0; i < 2; i++) agv[i * 64 + lane] = pg[i * 64 + lane];
    const float4* cg  = (const float4*)(Cmat + (size_t)base0 * 16);
    float4*       cmv = (float4*)cm;
    cmv[lane] = cg[lane];
    __syncthreads();

    float h[N_];
    #pragma unroll
    for (int n = 0; n < N_; n++)
        h[n] = S[(size_t)(gc * N_ + n) * D_ + lane];

    for (int s = 0; s < CHUNK; s++) {
        float xd = xs[s * D_ + lane];
        const float4* row = (const float4*)(ag + s * 32);
        const float4* crw = (const float4*)(cm + s * 16);
        float acc = 0.0f;
        #pragma unroll
        for (int q = 0; q < 4; q++) {
            float4 a4 = row[q];
            float4 g4 = row[4 + q];
            float4 c4 = crw[q];
            h[4*q+0] = a4.x * h[4*q+0] + g4.x * xd;  acc += c4.x * h[4*q+0];
            h[4*q+1] = a4.y * h[4*q+1] + g4.y * xd;  acc += c4.y * h[4*q+1];
            h[4*q+2] = a4.z * h[4*q+2] + g4.z * xd;  acc += c4.z * h[4*q+2];
            h[4*q+3] = a4.w * h[4*q+3] + g4.w * xd;  acc += c4.w * h[4*q+3];
        }
        out[(size_t)(base0 + s) * D_ + lane] = acc;
    }
}

// ---------------------------------------------------------------------------
extern "C" void kernel_launch(void* const* d_in, const int* in_sizes, int n_in,
                              void* d_out, int out_size, void* d_ws, size_t ws_size,
                              hipStream_t stream)
{
    const float* x  = (const float*)d_in[0];
    const float* A  = (const float*)d_in[1];
    const float* Wb = (const float*)d_in[2];
    const float* bb = (const float*)d_in[3];
    const float* Wc = (const float*)d_in[4];
    const float* bc = (const float*)d_in[5];
    const float* Wd = (const float*)d_in[6];
    const float* bd = (const float*)d_in[7];
    float* out = (float*)d_out;

    // ws carve (floats): P 524288 | Cm 262144 | S 1048576 | Cdec 16384 | ctr 4
    float* P    = (float*)d_ws;
    float* Cm   = P  + (size_t)B_ * L_ * 32;
    float* S    = Cm + (size_t)B_ * L_ * 16;
    float* Cdec = S  + (size_t)TOTCHUNK * N_ * D_;
    int*   ctr  = (int*)(Cdec + (size_t)TOTCHUNK * N_);

    hipMemsetAsync(ctr, 0, B_ * sizeof(int), stream);
    proj_scan_combine_kernel<<<TOTCHUNK, 64, 0, stream>>>(
        x, A, Wb, bb, Wc, bc, Wd, bd, P, Cm, S, Cdec, ctr);
    scan_out<<<TOTCHUNK, 64, 0, stream>>>(x, P, Cm, S, out);
}

// Round 7
// 103.410 us; speedup vs baseline: 1.4909x; 1.4909x over previous
//
#include <hip/hip_runtime.h>

#define B_ 4
#define L_ 4096
#define D_ 64
#define N_ 16
#define CHUNK 16
#define NCHUNK (L_ / CHUNK)        // 256
#define TOTCHUNK (B_ * NCHUNK)     // 1024

constexpr float DT_  = 0.1f;
constexpr float EPS_ = 1e-6f;

// ---------------------------------------------------------------------------
// K1: fused projection + local chunk scan + LOCAL output + correction matrix.
// 1024 blocks x 64 threads (1 wave). Per block (= one 16-step chunk):
//   stage x -> LDS; 16 interleaved delta butterflies; Bm/Cm dots (W rows in
//   registers) -> a/g/cm in LDS; local scan with ZERO init, writing the
//   local output out_local[l,d] = sum_n cm_l[n]*h_local_l[n,d] directly to
//   out; store chunk-final local state -> S; store chunk decay -> Cdec; and
//   store Wc_l[n] = cm_l[n] * prod_{j<=l} a_j[n]  (correction matrix) so the
//   final kernel can add  sum_n Wc_l[n]*init[n,d]  without replaying.
// NO spin/sync: plain 3-dispatch pipeline (R6's spin-wait was a disaster).
// ---------------------------------------------------------------------------
__global__ __launch_bounds__(64) void proj_scan_kernel(
    const float* __restrict__ x,  const float* __restrict__ A,
    const float* __restrict__ Wb, const float* __restrict__ bb,
    const float* __restrict__ Wc, const float* __restrict__ bc,
    const float* __restrict__ Wd, const float* __restrict__ bd,
    float* __restrict__ S, float* __restrict__ Cdec,
    float* __restrict__ Wcor, float* __restrict__ out)
{
    const int gc    = blockIdx.x;              // global chunk 0..1023
    const int batch = gc >> 8;                 // gc / NCHUNK
    const int c     = gc & (NCHUNK - 1);
    const int lane  = threadIdx.x;
    const int base0 = batch * L_ + c * CHUNK;

    __shared__ float xs[CHUNK * D_];           // 4 KB
    __shared__ float ag[CHUNK * 32];           // 2 KB
    __shared__ float cm[CHUNK * N_];           // 1 KB
    __shared__ float wbuf[CHUNK * N_];         // 1 KB

    // ---- stage chunk's x ----
    const float4* xg  = (const float4*)(x + (size_t)base0 * D_);
    float4*       xsv = (float4*)xs;
    #pragma unroll
    for (int i = 0; i < 4; i++) xsv[i * 64 + lane] = xg[i * 64 + lane];

    // ---- W rows in registers (overlaps x staging latency) ----
    const int o  = lane & 31;                  // 0-15 -> Bm row, 16-31 -> Cm row
    const int h2 = lane >> 5;                  // K-half
    float wreg[32];
    const float* Wrow = (o < 16) ? (Wb + o * D_) : (Wc + (o - 16) * D_);
    const float4* w4p = (const float4*)(Wrow + h2 * 32);
    #pragma unroll
    for (int j = 0; j < 8; j++) {
        float4 w4 = w4p[j];
        wreg[4*j+0] = w4.x; wreg[4*j+1] = w4.y;
        wreg[4*j+2] = w4.z; wreg[4*j+3] = w4.w;
    }
    const float wd   = Wd[lane];
    const float bd0  = bd[0];
    const float An   = A[lane & 15];           // row 0 of (D,N); rows identical
    const float bias = (o < 16) ? bb[o] : bc[o - 16];

    __syncthreads();

    // ---- deltas: 16 butterflies, interleaved so shfl chains pipeline ----
    float r[CHUNK];
    #pragma unroll
    for (int p = 0; p < CHUNK; p++) r[p] = xs[p * D_ + lane] * wd;
    #pragma unroll
    for (int m = 32; m >= 1; m >>= 1) {
        #pragma unroll
        for (int p = 0; p < CHUNK; p++) r[p] += __shfl_xor(r[p], m, 64);
    }
    float delta[CHUNK];
    #pragma unroll
    for (int p = 0; p < CHUNK; p++) {
        float z = r[p] + bd0;
        delta[p] = fmaxf(z, 0.0f) + log1pf(expf(-fabsf(z))) + DT_;
    }

    // ---- Bm/Cm dots -> LDS ----
    #pragma unroll
    for (int p = 0; p < CHUNK; p++) {
        float acc = 0.0f;
        const float4* xs4 = (const float4*)(xs + p * D_ + h2 * 32);
        #pragma unroll
        for (int j = 0; j < 8; j++) {
            float4 v = xs4[j];                 // broadcast LDS reads
            acc += v.x * wreg[4*j+0] + v.y * wreg[4*j+1]
                 + v.z * wreg[4*j+2] + v.w * wreg[4*j+3];
        }
        acc += __shfl_xor(acc, 32, 64);        // lanes 0-31 hold full dots
        if (lane < 16) {
            float Bm  = acc + bias;
            float tmp = An * delta[p];
            float a   = expf(tmp);
            float g   = (a - 1.0f) * delta[p] * Bm / (tmp + EPS_);
            ag[p * 32 + lane]      = a;
            ag[p * 32 + 16 + lane] = g;
        } else if (lane < 32) {
            cm[p * 16 + (lane - 16)] = acc + bias;
        }
    }
    __syncthreads();

    // ---- local scan (zero init) + local output, LDS-only inner loop ----
    float h[N_];
    #pragma unroll
    for (int n = 0; n < N_; n++) h[n] = 0.0f;
    for (int s = 0; s < CHUNK; s++) {
        float xd = xs[s * D_ + lane];
        const float4* row = (const float4*)(ag + s * 32);
        const float4* crw = (const float4*)(cm + s * 16);
        float acc = 0.0f;
        #pragma unroll
        for (int q = 0; q < 4; q++) {
            float4 a4 = row[q];
            float4 g4 = row[4 + q];
            float4 c4 = crw[q];
            h[4*q+0] = a4.x * h[4*q+0] + g4.x * xd;  acc += c4.x * h[4*q+0];
            h[4*q+1] = a4.y * h[4*q+1] + g4.y * xd;  acc += c4.y * h[4*q+1];
            h[4*q+2] = a4.z * h[4*q+2] + g4.z * xd;  acc += c4.z * h[4*q+2];
            h[4*q+3] = a4.w * h[4*q+3] + g4.w * xd;  acc += c4.w * h[4*q+3];
        }
        out[(size_t)(base0 + s) * D_ + lane] = acc;   // local (zero-init) output
    }
    #pragma unroll
    for (int n = 0; n < N_; n++)
        S[(size_t)(gc * N_ + n) * D_ + lane] = h[n];  // chunk-final local state

    // ---- correction matrix + chunk decay (lanes 0..15, lane = n) ----
    if (lane < 16) {
        float cumn = 1.0f;
        for (int s = 0; s < CHUNK; s++) {
            cumn *= ag[s * 32 + lane];                 // prod of a up to s incl.
            wbuf[s * 16 + lane] = cm[s * 16 + lane] * cumn;
        }
        Cdec[gc * N_ + lane] = cumn;
    }
    __syncthreads();
    // coalesced blast of wbuf -> global Wcor (256 floats = 64 float4)
    ((float4*)(Wcor + (size_t)base0 * 16))[lane] = ((const float4*)wbuf)[lane];
}

// ---------------------------------------------------------------------------
// K2: cross-chunk exclusive scan, 64 blocks x 64 threads; block = (b,n),
// thread = d. Groups of 32 with next-group prefetch: 64 loads in flight while
// a group is processed (~550 cy) >= remote-L2/IF latency (~500 cy), so the
// serial chain runs nearly stall-free. (R5's distance-4 exposed ~450 cy/grp.)
// ---------------------------------------------------------------------------
#define G_ 32
__global__ __launch_bounds__(64) void combine(
    float* __restrict__ S, const float* __restrict__ Cdec)
{
    const int b = blockIdx.x >> 4;
    const int n = blockIdx.x & 15;
    const int d = threadIdx.x;
    const int cb = b * NCHUNK;

    float*       baseS = S    + (size_t)(cb * N_ + n) * D_ + d;  // stride N_*D_ per chunk
    const float* baseA = Cdec + cb * N_ + n;                     // stride N_ per chunk

    float run = 0.0f;
    float sbuf[G_], abuf[G_];
    #pragma unroll
    for (int j = 0; j < G_; j++) {
        sbuf[j] = baseS[(size_t)j * (N_ * D_)];
        abuf[j] = baseA[j * N_];
    }
    for (int cc = 0; cc < NCHUNK; cc += G_) {
        const int cn = (cc + G_ < NCHUNK) ? (cc + G_) : cc;   // last: dummy reload
        float t[G_], u[G_];
        #pragma unroll
        for (int j = 0; j < G_; j++) {
            t[j] = baseS[(size_t)(cn + j) * (N_ * D_)];
            u[j] = baseA[(cn + j) * N_];
        }
        #pragma unroll
        for (int j = 0; j < G_; j++) {
            baseS[(size_t)(cc + j) * (N_ * D_)] = run;        // exclusive prefix
            run = abuf[j] * run + sbuf[j];
        }
        #pragma unroll
        for (int j = 0; j < G_; j++) { sbuf[j] = t[j]; abuf[j] = u[j]; }
    }
}

// ---------------------------------------------------------------------------
// K3: apply correction: out[l,d] += sum_n Wcor_l[n] * init[n,d].
// 1024 blocks x 64 threads. No x/ag staging, no scan replay.
// ---------------------------------------------------------------------------
__global__ __launch_bounds__(64) void apply_kernel(
    const float* __restrict__ Wcor, const float* __restrict__ S,
    float* __restrict__ out)
{
    const int gc    = blockIdx.x;
    const int batch = gc >> 8;
    const int c     = gc & (NCHUNK - 1);
    const int lane  = threadIdx.x;
    const int base0 = batch * L_ + c * CHUNK;

    __shared__ float wl[CHUNK * N_];           // 1 KB

    // stage correction matrix (256 floats = 64 float4, one per lane)
    ((float4*)wl)[lane] = ((const float4*)(Wcor + (size_t)base0 * 16))[lane];

    // chunk-initial state (post-combine S)
    float hi[N_];
    #pragma unroll
    for (int n = 0; n < N_; n++)
        hi[n] = S[(size_t)(gc * N_ + n) * D_ + lane];

    // preload local outputs for RMW
    float4 ov[4];
    const float4* og = (const float4*)(out + (size_t)base0 * D_);
    #pragma unroll
    for (int i = 0; i < 4; i++) ov[i] = og[i * 64 + lane];

    __syncthreads();

    float acc[CHUNK];
    #pragma unroll
    for (int s = 0; s < CHUNK; s++) {
        const float4* crw = (const float4*)(wl + s * 16);
        float a = 0.0f;
        #pragma unroll
        for (int q = 0; q < 4; q++) {
            float4 w4 = crw[q];
            a += w4.x * hi[4*q+0] + w4.y * hi[4*q+1]
               + w4.z * hi[4*q+2] + w4.w * hi[4*q+3];
        }
        acc[s] = a;
    }

    // RMW store: out_local + correction. Lane owns element d of 4 different
    // positions per float4 group: group i covers positions s = i*4.. no —
    // layout: og[i*64+lane] is position s=(i*64+lane)>>4? No: positions are
    // rows of 64 floats; float4 index i*64+lane covers position (i*64+lane)/16.
    // Simpler: lane's float4 i sits at flat offset (i*64+lane)*4 floats →
    // position p = (i*64+lane)>>4, and its 4 elements are consecutive d's of
    // that single position. So each float4 gets acc[p] added? NO — acc is
    // per-(position, this lane's d). Use scalar RMW instead (still coalesced).
    #pragma unroll
    for (int s = 0; s < CHUNK; s++)
        out[(size_t)(base0 + s) * D_ + lane] = out[(size_t)(base0 + s) * D_ + lane] + acc[s];
}

// ---------------------------------------------------------------------------
extern "C" void kernel_launch(void* const* d_in, const int* in_sizes, int n_in,
                              void* d_out, int out_size, void* d_ws, size_t ws_size,
                              hipStream_t stream)
{
    const float* x  = (const float*)d_in[0];
    const float* A  = (const float*)d_in[1];
    const float* Wb = (const float*)d_in[2];
    const float* bb = (const float*)d_in[3];
    const float* Wc = (const float*)d_in[4];
    const float* bc = (const float*)d_in[5];
    const float* Wd = (const float*)d_in[6];
    const float* bd = (const float*)d_in[7];
    float* out = (float*)d_out;

    // ws carve (floats): S 1048576 (4MB) | Cdec 16384 | Wcor 262144 (1MB)
    float* S    = (float*)d_ws;
    float* Cdec = S    + (size_t)TOTCHUNK * N_ * D_;
    float* Wcor = Cdec + (size_t)TOTCHUNK * N_;

    proj_scan_kernel<<<TOTCHUNK, 64, 0, stream>>>(x, A, Wb, bb, Wc, bc, Wd, bd,
                                                  S, Cdec, Wcor, out);
    combine<<<B_ * N_, 64, 0, stream>>>(S, Cdec);
    apply_kernel<<<TOTCHUNK, 64, 0, stream>>>(Wcor, S, out);
}